// Round 2
// baseline (304.252 us; speedup 1.0000x reference)
//
#include <hip/hip_runtime.h>
#include <math.h>

#define N_NODES 100000
#define N_EDGES 1600000
#define G_GRAPHS 256
#define IN_F 128
#define H_F 64

// src histogram (for ns): byte-packed counts, quarter-range LDS windows
#define HB 40                  // edge chunks
#define HCHUNK (N_EDGES / HB)  // 40000
#define NWORDS (N_NODES / 4)   // 25000 packed-u8 words
#define HNODES 25000           // nodes per window
#define HWORDS (HNODES / 4)    // 6250 words (25 KB LDS)
#define HR 4                   // windows

// CSR build via dst-range bucketing
#define NREG 160               // regions (one block each in phase 2)
#define REG_NODES 625          // nodes per region
#define BUCKET_CAP 11000       // max edges/region (mean 10000, sigma ~100)
#define BSPAN 6400             // edges per bucket block
#define NB_BUCKET (N_EDGES / BSPAN)  // 250

typedef unsigned int uint_t;
typedef unsigned short ushort_t;
typedef unsigned char uchar_t;
typedef __attribute__((ext_vector_type(8))) short short8;
typedef __attribute__((ext_vector_type(4))) float floatx4;
typedef __attribute__((ext_vector_type(2))) float floatx2;

constexpr int WROW_F = H_F + 8;  // 72 shorts = 144 B rows, 16B-aligned

__device__ __forceinline__ ushort_t f2bf(float f) {  // round-to-nearest-even
  uint_t u = __float_as_uint(f);
  uint_t r = (u + 0x7fffu + ((u >> 16) & 1u)) >> 16;
  return (ushort_t)r;
}
__device__ __forceinline__ float bflo(uint_t u) { return __uint_as_float(u << 16); }
__device__ __forceinline__ uchar_t f2fp8(float f) {
  return (uchar_t)(__builtin_amdgcn_cvt_pk_fp8_f32(f, f, 0, false) & 0xff);
}

// ---------------------------------------------------------------------------
// 1. Merged launch A: blocks [0,250) bucket edges by dst region;
//    blocks [250,410) byte-packed src histogram.
// ---------------------------------------------------------------------------
__global__ __launch_bounds__(256) void build_a_kernel(
    const int* __restrict__ src, const int* __restrict__ dst,
    const float* __restrict__ ew, int* __restrict__ bcnt,
    uint2* __restrict__ bucket, uint_t* __restrict__ p8src) {
  __shared__ uint_t shm[BSPAN + 2 * NREG];  // bucket: rl+cnt+cur; hist: 6250
  if (blockIdx.x < NB_BUCKET) {
    uint_t* rl = shm;                 // BSPAN
    int* cnt = (int*)(shm + BSPAN);   // NREG
    int* cur = cnt + NREG;            // NREG
    const int e0 = blockIdx.x * BSPAN;

    for (int i = threadIdx.x; i < NREG; i += 256) cnt[i] = 0;
    __syncthreads();

    for (int i = threadIdx.x; i < BSPAN; i += 256) {
      uint_t d = (uint_t)dst[e0 + i];
      uint_t r = d / REG_NODES;
      uint_t loc = d - r * REG_NODES;
      rl[i] = (r << 16) | loc;
      atomicAdd(&cnt[r], 1);
    }
    __syncthreads();

    for (int i = threadIdx.x; i < NREG; i += 256)
      cur[i] = atomicAdd(&bcnt[i], cnt[i]);
    __syncthreads();

    for (int i = threadIdx.x; i < BSPAN; i += 256) {
      uint_t v = rl[i];
      uint_t r = v >> 16, loc = v & 0xffffu;
      int pos = atomicAdd(&cur[r], 1);
      if (pos < BUCKET_CAP)
        bucket[(size_t)r * BUCKET_CAP + pos] = make_uint2(
            (loc << 17) | (uint_t)src[e0 + i], __float_as_uint(ew[e0 + i]));
    }
  } else {
    uint_t* h = shm;
    const int idx = blockIdx.x - NB_BUCKET;
    const int r = idx / HB;
    const int b = idx % HB;
    const uint_t rbase = (uint_t)(r * HNODES);

    for (int i = threadIdx.x; i < HWORDS; i += 256) h[i] = 0u;
    __syncthreads();

    const uint4* k4 = (const uint4*)(src + b * HCHUNK);
    for (int i = threadIdx.x; i < HCHUNK / 4; i += 256) {
      uint4 v = k4[i];
      uint_t t;
      t = v.x - rbase; if (t < (uint_t)HNODES) atomicAdd(&h[t >> 2], 1u << ((t & 3u) * 8u));
      t = v.y - rbase; if (t < (uint_t)HNODES) atomicAdd(&h[t >> 2], 1u << ((t & 3u) * 8u));
      t = v.z - rbase; if (t < (uint_t)HNODES) atomicAdd(&h[t >> 2], 1u << ((t & 3u) * 8u));
      t = v.w - rbase; if (t < (uint_t)HNODES) atomicAdd(&h[t >> 2], 1u << ((t & 3u) * 8u));
    }
    __syncthreads();

    uint_t* outp = p8src + (size_t)b * NWORDS + r * HWORDS;
    for (int i = threadIdx.x; i < HWORDS; i += 256) outp[i] = h[i];
  }
}

// ---------------------------------------------------------------------------
// 2. Merged launch B (1024 threads): blocks [0,160) region place (csr+rc+nd);
//    blocks [160,185) ns from src histogram.
// ---------------------------------------------------------------------------
__global__ __launch_bounds__(1024) void build_b_kernel(
    const uint2* __restrict__ bucket, const int* __restrict__ bcnt,
    const uint_t* __restrict__ p8src, uint_t* __restrict__ csr,
    int2* __restrict__ rc, float* __restrict__ nd, float* __restrict__ ns) {
  __shared__ uint_t staged[BUCKET_CAP];   // 44 KB
  __shared__ int cnt[REG_NODES];
  __shared__ int sc[REG_NODES];
  __shared__ int ts[1024];
  const int tid = threadIdx.x;
  if (blockIdx.x >= NREG) {
    // ns blocks
    int w = (blockIdx.x - NREG) * 1024 + tid;
    if (w >= NWORDS) return;
    int c0 = 0, c1 = 0, c2 = 0, c3 = 0;
    for (int b = 0; b < HB; ++b) {
      uint_t xv = p8src[(size_t)b * NWORDS + w];
      c0 += (int)(xv & 0xffu);
      c1 += (int)((xv >> 8) & 0xffu);
      c2 += (int)((xv >> 16) & 0xffu);
      c3 += (int)((xv >> 24) & 0xffu);
    }
    ((float4*)ns)[w] = make_float4(
        rsqrtf(fmaxf((float)c0, 1.0f)), rsqrtf(fmaxf((float)c1, 1.0f)),
        rsqrtf(fmaxf((float)c2, 1.0f)), rsqrtf(fmaxf((float)c3, 1.0f)));
    return;
  }
  const int r = blockIdx.x;
  const int nE = min(bcnt[r], BUCKET_CAP);

  // csr base = exclusive prefix of bcnt over regions (NREG=160 < 256)
  ts[tid] = (tid < NREG) ? min(bcnt[tid], BUCKET_CAP) : 0;
  for (int i = tid; i < REG_NODES; i += 1024) cnt[i] = 0;
  __syncthreads();
  for (int off = 1; off < 256; off <<= 1) {
    int t = (tid >= off) ? ts[tid - off] : 0;
    __syncthreads();
    ts[tid] += t;
    __syncthreads();
  }
  const int csr_base = (r == 0) ? 0 : ts[r - 1];
  __syncthreads();

  // pass A: per-node counts
  const uint2* bk = bucket + (size_t)r * BUCKET_CAP;
  for (int i = tid; i < nE; i += 1024) atomicAdd(&cnt[bk[i].x >> 17], 1);
  __syncthreads();

  // exclusive scan over REG_NODES counts (1 per thread, 625 <= 1024)
  int cv = (tid < REG_NODES) ? cnt[tid] : 0;
  ts[tid] = cv;
  __syncthreads();
  for (int off = 1; off < 1024; off <<= 1) {
    int t = (tid >= off) ? ts[tid - off] : 0;
    __syncthreads();
    ts[tid] += t;
    __syncthreads();
  }
  if (tid < REG_NODES) {
    int run = (tid == 0) ? 0 : ts[tid - 1];
    sc[tid] = run;
    int v = r * REG_NODES + tid;
    rc[v] = make_int2(csr_base + run, cv);
    nd[v] = rsqrtf(fmaxf((float)cv, 1.0f));
  }
  __syncthreads();

  // pass B: place into staged slice
  for (int i = tid; i < nE; i += 1024) {
    uint2 e = bk[i];
    uint_t loc = e.x >> 17;
    int pos = atomicAdd(&sc[loc], 1);
    staged[pos] = ((uint_t)(f2bf(__uint_as_float(e.y)) & 0x7fff) << 17) |
                  (e.x & 0x1ffffu);
  }
  __syncthreads();

  // coalesced stream-out
  for (int i = tid; i < nE; i += 1024) csr[csr_base + i] = staged[i];
}

// ---------------------------------------------------------------------------
// 3. MFMA GEMM (layer 1 only): T[i,:] = fp8(ns[i] * (X[i,:] @ W))
// ---------------------------------------------------------------------------
template <int K, bool AFP32>
__global__ __launch_bounds__(256) void gemm_mfma_kernel(
    const void* __restrict__ Xin, const float* __restrict__ W,
    const float* __restrict__ ns, uchar_t* __restrict__ T, int ntiles) {
  constexpr int CH = K / 32;
  constexpr int WROW = K + 8;
  __shared__ __align__(16) ushort_t Wt[64 * WROW];
  const int tid = threadIdx.x;

  for (int i = tid; i < K * 64; i += 256) {
    int k = i >> 6, nn = i & 63;
    Wt[nn * WROW + k] = f2bf(W[i]);
  }
  __syncthreads();

  const int wave = tid >> 6;
  const int lane = tid & 63;
  const int tile = blockIdx.x * 4 + wave;
  if (tile >= ntiles) return;
  const int m = lane & 15;
  const int q = lane >> 4;
  const int node0 = tile * 16;

  short8 afrag[CH];
  if (AFP32) {
    const float* xr = (const float*)Xin + (size_t)(node0 + m) * K + q * 8;
#pragma unroll
    for (int c = 0; c < CH; ++c) {
      float4 xa = *(const float4*)(xr + c * 32);
      float4 xb = *(const float4*)(xr + c * 32 + 4);
      short8 a;
      a[0] = (short)f2bf(xa.x); a[1] = (short)f2bf(xa.y);
      a[2] = (short)f2bf(xa.z); a[3] = (short)f2bf(xa.w);
      a[4] = (short)f2bf(xb.x); a[5] = (short)f2bf(xb.y);
      a[6] = (short)f2bf(xb.z); a[7] = (short)f2bf(xb.w);
      afrag[c] = a;
    }
  } else {
    const ushort_t* xr = (const ushort_t*)Xin + (size_t)(node0 + m) * K + q * 8;
#pragma unroll
    for (int c = 0; c < CH; ++c)
      afrag[c] = *(const short8*)(xr + c * 32);
  }

  floatx4 acc[4];
#pragma unroll
  for (int t = 0; t < 4; ++t) acc[t] = (floatx4){0.f, 0.f, 0.f, 0.f};

#pragma unroll
  for (int t = 0; t < 4; ++t) {
    const ushort_t* wr = &Wt[(t * 16 + m) * WROW + q * 8];
#pragma unroll
    for (int c = 0; c < CH; ++c) {
      short8 bfrag = *(const short8*)(wr + c * 32);
      acc[t] = __builtin_amdgcn_mfma_f32_16x16x32_bf16(afrag[c], bfrag, acc[t], 0, 0, 0);
    }
  }

  float4 nsv = *(const float4*)(ns + node0 + q * 4);
  const float nsa[4] = {nsv.x, nsv.y, nsv.z, nsv.w};
#pragma unroll
  for (int t = 0; t < 4; ++t) {
#pragma unroll
    for (int r = 0; r < 4; ++r) {
      int node = node0 + q * 4 + r;
      T[(size_t)node * 64 + t * 16 + m] = f2fp8(acc[t][r] * nsa[r]);
    }
  }
}

// ---------------------------------------------------------------------------
// 4. Fused gather + next-layer GEMM. Dual-node per thread: each thread owns
//    node A (rows 0..31) and node B (rows 32..63) concurrently, 8-deep load
//    batches each -> 16 T-row loads in flight per lane (latency-bound fix).
// ---------------------------------------------------------------------------
__device__ __forceinline__ void ld_e8(const uint_t* __restrict__ c, int k,
                                      uint_t e[8]) {
#pragma unroll
  for (int j = 0; j < 8; ++j) e[j] = c[k + j];
}
__device__ __forceinline__ void ld_p8(const uchar_t* __restrict__ T, int l,
                                      const uint_t e[8], uint2 p[8]) {
#pragma unroll
  for (int j = 0; j < 8; ++j)
    p[j] = *((const uint2*)(T + (size_t)(e[j] & 0x1ffffu) * 64) + l);
}
__device__ __forceinline__ void gacc1(float acc[8], uint_t e, uint2 p) {
  float w = __uint_as_float((e >> 17) << 16);
  floatx2 a;
  a = __builtin_amdgcn_cvt_pk_f32_fp8(p.x, false);
  acc[0] = fmaf(a.x, w, acc[0]); acc[1] = fmaf(a.y, w, acc[1]);
  a = __builtin_amdgcn_cvt_pk_f32_fp8(p.x, true);
  acc[2] = fmaf(a.x, w, acc[2]); acc[3] = fmaf(a.y, w, acc[3]);
  a = __builtin_amdgcn_cvt_pk_f32_fp8(p.y, false);
  acc[4] = fmaf(a.x, w, acc[4]); acc[5] = fmaf(a.y, w, acc[5]);
  a = __builtin_amdgcn_cvt_pk_f32_fp8(p.y, true);
  acc[6] = fmaf(a.x, w, acc[6]); acc[7] = fmaf(a.y, w, acc[7]);
}
__device__ __forceinline__ void gacc8(float acc[8], const uint_t e[8],
                                      const uint2 p[8]) {
#pragma unroll
  for (int j = 0; j < 8; ++j) gacc1(acc, e[j], p[j]);
}
__device__ __forceinline__ void ld_e4(const uint_t* __restrict__ c, int k,
                                      uint_t e[4]) {
#pragma unroll
  for (int j = 0; j < 4; ++j) e[j] = c[k + j];
}
__device__ __forceinline__ void ld_p4(const uchar_t* __restrict__ T, int l,
                                      const uint_t e[4], uint2 p[4]) {
#pragma unroll
  for (int j = 0; j < 4; ++j)
    p[j] = *((const uint2*)(T + (size_t)(e[j] & 0x1ffffu) * 64) + l);
}
__device__ __forceinline__ void gacc4(float acc[8], const uint_t e[4],
                                      const uint2 p[4]) {
#pragma unroll
  for (int j = 0; j < 4; ++j) gacc1(acc, e[j], p[j]);
}

__device__ __forceinline__ void hs_store(ushort_t* Hs, int row, int l,
                                         const float acc[8], float ndv,
                                         float4 b0, float4 b1v) {
  uint4 ov;
  ov.x = (uint_t)f2bf(fmaxf(fmaf(acc[0], ndv, b0.x), 0.f)) |
         ((uint_t)f2bf(fmaxf(fmaf(acc[1], ndv, b0.y), 0.f)) << 16);
  ov.y = (uint_t)f2bf(fmaxf(fmaf(acc[2], ndv, b0.z), 0.f)) |
         ((uint_t)f2bf(fmaxf(fmaf(acc[3], ndv, b0.w), 0.f)) << 16);
  ov.z = (uint_t)f2bf(fmaxf(fmaf(acc[4], ndv, b1v.x), 0.f)) |
         ((uint_t)f2bf(fmaxf(fmaf(acc[5], ndv, b1v.y), 0.f)) << 16);
  ov.w = (uint_t)f2bf(fmaxf(fmaf(acc[6], ndv, b1v.z), 0.f)) |
         ((uint_t)f2bf(fmaxf(fmaf(acc[7], ndv, b1v.w), 0.f)) << 16);
  *((uint4*)&Hs[row * WROW_F + l * 8]) = ov;
}

__device__ __forceinline__ void pool_acc(float* gaccF, float* pooled, int g,
                                         int g0s, int l, const float acc[8],
                                         float ndv, float4 b0, float4 b1v) {
  const float bb[8] = {b0.x, b0.y, b0.z, b0.w, b1v.x, b1v.y, b1v.z, b1v.w};
  float vals[8];
#pragma unroll
  for (int f = 0; f < 8; ++f)
    vals[f] = bflo((uint_t)f2bf(fmaxf(fmaf(acc[f], ndv, bb[f]), 0.f)));
  int gl = g - g0s;
  if (gl >= 0 && gl < 4) {
#pragma unroll
    for (int f = 0; f < 8; ++f)
      atomicAdd(&gaccF[gl * 64 + l * 8 + f], vals[f]);
  } else {
#pragma unroll
    for (int f = 0; f < 8; ++f)
      atomicAdd(&pooled[(size_t)g * 64 + l * 8 + f], vals[f]);
  }
}

template <bool POOL>
__global__ __launch_bounds__(256, 4) void fused_kernel(
    const uint_t* __restrict__ csr, const int2* __restrict__ rc,
    const uchar_t* __restrict__ T, const float* __restrict__ nd,
    const float* __restrict__ bias, const float* __restrict__ ns,
    const float* __restrict__ W, uchar_t* __restrict__ Tout,
    const int* __restrict__ gid, float* __restrict__ pooled) {
  __shared__ __align__(16) ushort_t Hs[64 * WROW_F];
  __shared__ __align__(16) ushort_t Wt[64 * WROW_F];
  __shared__ float gaccF[4 * 64];
  __shared__ int g0s;
  const int tid = threadIdx.x;
  const int node_base = blockIdx.x * 64;

  if constexpr (POOL) {
    gaccF[tid] = 0.0f;  // 4*64 == 256
    if (tid == 0) g0s = gid[node_base];
  } else {
    for (int i = tid; i < H_F * 64; i += 256) {
      int k = i >> 6, nn = i & 63;
      Wt[nn * WROW_F + k] = f2bf(W[i]);
    }
  }
  __syncthreads();

  const int lane = tid & 63;
  const int wv = tid >> 6;
  const int o = lane >> 3, l = lane & 7;

  const int ln = wv * 8 + o;            // 0..31
  const int vA = node_base + ln;        // always < N (grid covers N, A-half)
  const int vB = vA + 32;
  const bool bok = (vB < N_NODES);

  int2 rcA = rc[vA];
  int2 rcB = bok ? rc[vB] : make_int2(0, 0);
  const uint_t* cA = csr + rcA.x;
  const uint_t* cB = csr + rcB.x;
  const int cntA = rcA.y, cntB = rcB.y;

  float accA[8] = {0, 0, 0, 0, 0, 0, 0, 0};
  float accB[8] = {0, 0, 0, 0, 0, 0, 0, 0};
  int kA = 0, kB = 0;

  // joint 8+8 chunks: 16 T-row loads in flight
  while ((kA + 8 <= cntA) && (kB + 8 <= cntB)) {
    uint_t eA[8], eB[8];
    uint2 pA[8], pB[8];
    ld_e8(cA, kA, eA);
    ld_e8(cB, kB, eB);
    ld_p8(T, l, eA, pA);
    ld_p8(T, l, eB, pB);
    gacc8(accA, eA, pA);
    gacc8(accB, eB, pB);
    kA += 8;
    kB += 8;
  }
  while (kA + 8 <= cntA) {
    uint_t e[8]; uint2 p[8];
    ld_e8(cA, kA, e); ld_p8(T, l, e, p); gacc8(accA, e, p); kA += 8;
  }
  while (kB + 8 <= cntB) {
    uint_t e[8]; uint2 p[8];
    ld_e8(cB, kB, e); ld_p8(T, l, e, p); gacc8(accB, e, p); kB += 8;
  }
  // 4-chunks (at most one each); issue both before consuming
  {
    const bool a4 = (kA + 4 <= cntA), b4 = (kB + 4 <= cntB);
    uint_t e4a[4], e4b[4];
    uint2 p4a[4], p4b[4];
    if (a4) { ld_e4(cA, kA, e4a); ld_p4(T, l, e4a, p4a); }
    if (b4) { ld_e4(cB, kB, e4b); ld_p4(T, l, e4b, p4b); }
    if (a4) { gacc4(accA, e4a, p4a); kA += 4; }
    if (b4) { gacc4(accB, e4b, p4b); kB += 4; }
  }
  for (; kA < cntA; ++kA) {
    uint_t e = cA[kA];
    uint2 p = *((const uint2*)(T + (size_t)(e & 0x1ffffu) * 64) + l);
    gacc1(accA, e, p);
  }
  for (; kB < cntB; ++kB) {
    uint_t e = cB[kB];
    uint2 p = *((const uint2*)(T + (size_t)(e & 0x1ffffu) * 64) + l);
    gacc1(accB, e, p);
  }

  const float4 b0 = *(const float4*)&bias[l * 8];
  const float4 b1v = *(const float4*)&bias[l * 8 + 4];
  const float ndA = nd[vA];
  const float ndB = bok ? nd[vB] : 0.0f;

  if constexpr (!POOL) {
    hs_store(Hs, ln, l, accA, ndA, b0, b1v);
    if (bok) hs_store(Hs, ln + 32, l, accB, ndB, b0, b1v);
  } else {
    pool_acc(gaccF, pooled, gid[vA], g0s, l, accA, ndA, b0, b1v);
    if (bok) pool_acc(gaccF, pooled, gid[vB], g0s, l, accB, ndB, b0, b1v);
  }
  __syncthreads();

  if constexpr (!POOL) {
    const int m = lane & 15, q = lane >> 4;
    const int node0 = node_base + wv * 16;
    if (node0 < N_NODES) {  // N % 16 == 0, so node0 < N implies a full tile
      short8 afrag[2];
      const ushort_t* xr = &Hs[(wv * 16 + m) * WROW_F + q * 8];
      afrag[0] = *(const short8*)(xr);
      afrag[1] = *(const short8*)(xr + 32);

      floatx4 acc4v[4];
#pragma unroll
      for (int t = 0; t < 4; ++t) acc4v[t] = (floatx4){0.f, 0.f, 0.f, 0.f};
#pragma unroll
      for (int t = 0; t < 4; ++t) {
        const ushort_t* wr = &Wt[(t * 16 + m) * WROW_F + q * 8];
#pragma unroll
        for (int c = 0; c < 2; ++c) {
          short8 bfrag = *(const short8*)(wr + c * 32);
          acc4v[t] = __builtin_amdgcn_mfma_f32_16x16x32_bf16(afrag[c], bfrag,
                                                            acc4v[t], 0, 0, 0);
        }
      }
      float4 nsv = *(const float4*)(ns + node0 + q * 4);
      const float nsa[4] = {nsv.x, nsv.y, nsv.z, nsv.w};
#pragma unroll
      for (int t = 0; t < 4; ++t) {
#pragma unroll
        for (int r2 = 0; r2 < 4; ++r2) {
          int node = node0 + q * 4 + r2;
          Tout[(size_t)node * 64 + t * 16 + m] = f2fp8(acc4v[t][r2] * nsa[r2]);
        }
      }
    }
  } else {
    int vlast = node_base + 63;
    if (vlast >= N_NODES) vlast = N_NODES - 1;
    int span = gid[vlast] - g0s + 1;
    if (span > 4) span = 4;
    if (tid < span * 64) {
      int gl = tid >> 6, j = tid & 63;
      int g = g0s + gl;
      if (g < G_GRAPHS) {
        float vsum = gaccF[gl * 64 + j];
        if (vsum != 0.0f) atomicAdd(&pooled[(size_t)g * 64 + j], vsum);
      }
    }
  }
}

// ---------------------------------------------------------------------------
// 5. Tiny pool finalize + MLP: reads pooled[G][64] (64 KB) instead of H.
// ---------------------------------------------------------------------------
__global__ __launch_bounds__(256) void pool_mlp_kernel(
    const float* __restrict__ pooled, const int* __restrict__ gid,
    const float* __restrict__ Dw1, const float* __restrict__ Db1,
    const float* __restrict__ Dw2, const float* __restrict__ Db2,
    const float* __restrict__ Dw3, const float* __restrict__ Db3,
    float* __restrict__ out) {
  __shared__ float mean[64];
  __shared__ float h1s[16], h2s[8];
  const int g = blockIdx.x;
  int l = 0, r = N_NODES;
  while (l < r) { int m = (l + r) >> 1; if (gid[m] < g) l = m + 1; else r = m; }
  const int lo = l;
  r = N_NODES;
  while (l < r) { int m = (l + r) >> 1; if (gid[m] < g + 1) l = m + 1; else r = m; }
  const int hi = l;

  if (threadIdx.x < 64) {
    float inv = 1.0f / fmaxf((float)(hi - lo), 1.0f);
    mean[threadIdx.x] = pooled[(size_t)g * 64 + threadIdx.x] * inv;
  }
  __syncthreads();
  if (threadIdx.x < 16) {
    int o = threadIdx.x;
    float a = Db1[o];
#pragma unroll
    for (int k = 0; k < 64; ++k) a = fmaf(mean[k], Dw1[k * 16 + o], a);
    h1s[o] = fmaxf(a, 0.0f);
  }
  __syncthreads();
  if (threadIdx.x < 8) {
    int o = threadIdx.x;
    float a = Db2[o];
#pragma unroll
    for (int k = 0; k < 16; ++k) a = fmaf(h1s[k], Dw2[k * 8 + o], a);
    h2s[o] = fmaxf(a, 0.0f);
  }
  __syncthreads();
  if (threadIdx.x == 0) {
    float a = Db3[0];
#pragma unroll
    for (int k = 0; k < 8; ++k) a = fmaf(h2s[k], Dw3[k], a);
    out[g] = 1.0f / (1.0f + expf(-a));
  }
}

// ---------------------------------------------------------------------------
extern "C" void kernel_launch(void* const* d_in, const int* in_sizes, int n_in,
                              void* d_out, int out_size, void* d_ws, size_t ws_size,
                              hipStream_t stream) {
  const float* x   = (const float*)d_in[0];
  const int*   src = (const int*)  d_in[1];
  const int*   dst = (const int*)  d_in[2];
  const float* ew  = (const float*)d_in[3];
  const int*   gid = (const int*)  d_in[4];
  const float* W1  = (const float*)d_in[5];
  const float* b1  = (const float*)d_in[6];
  const float* W2  = (const float*)d_in[7];
  const float* b2  = (const float*)d_in[8];
  const float* W3  = (const float*)d_in[9];
  const float* b3  = (const float*)d_in[10];
  const float* Dw1 = (const float*)d_in[11];
  const float* Db1 = (const float*)d_in[12];
  const float* Dw2 = (const float*)d_in[13];
  const float* Db2 = (const float*)d_in[14];
  const float* Dw3 = (const float*)d_in[15];
  const float* Db3 = (const float*)d_in[16];
  float* out = (float*)d_out;

  // workspace layout
  char* ws = (char*)d_ws;
  const size_t TSZ = (size_t)N_NODES * 64;                   // 6.4 MB
  const size_t BUCKET_BYTES = (size_t)NREG * BUCKET_CAP * 8; // 14.08 MB
  uchar_t*  T_a   = (uchar_t*)ws;                            // 6.4 MB
  uchar_t*  T_b   = (uchar_t*)(ws + TSZ);                    // 6.4 MB
  uint2*    bucket = (uint2*)ws;         // aliases T_a/T_b (dead after build_b)
  char* p = ws + BUCKET_BYTES;
  uint_t*   csr   = (uint_t*)p;          p += (size_t)N_EDGES * 4;      // 6.4 MB
  uint_t*   p8src = (uint_t*)p;          p += (size_t)HB * NWORDS * 4;  // 4 MB
  float*    ns    = (float*)p;           p += (size_t)N_NODES * 4;
  float*    nd    = (float*)p;           p += (size_t)N_NODES * 4;
  int2*     rc    = (int2*)p;            p += (size_t)N_NODES * 8;
  int*      bcnt  = (int*)p;             p += (size_t)NREG * 4;
  float*    pooled = (float*)p;          // 64 KB, contiguous after bcnt

  const int NTILES  = N_NODES / 16;                          // 6250
  const int NB_A    = NB_BUCKET + HR * HB;                   // 250+160 = 410
  const int NB_B    = NREG + (NWORDS + 1023) / 1024;         // 160+25 = 185
  const int NB_GEMM = (NTILES + 3) / 4;
  const int NB_F    = (N_NODES + 63) / 64;                   // 1563

  // ---- CSR build (2 merged launches + zero bcnt AND pooled in one memset)
  hipMemsetAsync(bcnt, 0,
                 NREG * sizeof(int) + G_GRAPHS * H_F * sizeof(float), stream);
  build_a_kernel<<<NB_A, 256, 0, stream>>>(src, dst, ew, bcnt, bucket, p8src);
  build_b_kernel<<<NB_B, 1024, 0, stream>>>(bucket, bcnt, p8src, csr, rc, nd, ns);

  // ---- layer 1: x(fp32,128) -> T_a   (overwrites bucket alias, post build_b)
  gemm_mfma_kernel<IN_F, true><<<NB_GEMM, 256, 0, stream>>>(x, W1, ns, T_a, NTILES);
  // ---- fused gather(L1)+gemm(L2): T_a -> T_b
  fused_kernel<false><<<NB_F, 256, 0, stream>>>(csr, rc, T_a, nd, b1, ns, W2,
                                                T_b, nullptr, nullptr);
  // ---- fused gather(L2)+gemm(L3): T_b -> T_a
  fused_kernel<false><<<NB_F, 256, 0, stream>>>(csr, rc, T_b, nd, b2, ns, W3,
                                                T_a, nullptr, nullptr);
  // ---- fused gather(L3)+pool: T_a -> pooled
  fused_kernel<true><<<NB_F, 256, 0, stream>>>(csr, rc, T_a, nd, b3, nullptr,
                                               nullptr, nullptr, gid, pooled);

  // ---- finalize pool + MLP
  pool_mlp_kernel<<<G_GRAPHS, 256, 0, stream>>>(pooled, gid, Dw1, Db1, Dw2, Db2,
                                                Dw3, Db3, out);
}

// Round 3
// 289.208 us; speedup vs baseline: 1.0520x; 1.0520x over previous
//
#include <hip/hip_runtime.h>
#include <math.h>

#define N_NODES 100000
#define N_EDGES 1600000
#define G_GRAPHS 256
#define IN_F 128
#define H_F 64

// src histogram (for ns): byte-packed counts, quarter-range LDS windows
#define HB 20                  // edge chunks
#define HCHUNK (N_EDGES / HB)  // 80000
#define NWORDS (N_NODES / 4)   // 25000 packed-u8 words
#define HNODES 25000           // nodes per window
#define HWORDS (HNODES / 4)    // 6250 words (25 KB LDS)
#define HR 4                   // windows

// CSR build via dst-range bucketing
#define NREG 160               // regions (one block each in phase 2)
#define REG_NODES 625          // nodes per region
#define BUCKET_CAP 11000       // max RAW edges/region (mean 10000, sigma ~100)
#define BSPAN 6400             // edges per bucket block
#define NB_BUCKET (N_EDGES / BSPAN)  // 250
// per-node slots padded to multiple of 4 (16B-aligned uint4 csr loads);
// pads decode to (row 0, w=0.0) == no-op. Region slack for pads:
#define RSLACK 1280            // mean pad/region 937, sigma 28 -> 12 sigma
#define STG_CAP 12880          // staged LDS entries (raw<=11000 + pads<=1875)
#define CSR_ALLOC 1806336      // sum of region allocs upper bound

typedef unsigned int uint_t;
typedef unsigned short ushort_t;
typedef unsigned char uchar_t;
typedef __attribute__((ext_vector_type(8))) short short8;
typedef __attribute__((ext_vector_type(4))) float floatx4;
typedef __attribute__((ext_vector_type(2))) float floatx2;

__device__ __forceinline__ ushort_t f2bf(float f) {  // round-to-nearest-even
  uint_t u = __float_as_uint(f);
  uint_t r = (u + 0x7fffu + ((u >> 16) & 1u)) >> 16;
  return (ushort_t)r;
}
__device__ __forceinline__ float bflo(uint_t u) { return __uint_as_float(u << 16); }
__device__ __forceinline__ uchar_t f2fp8(float f) {
  return (uchar_t)(__builtin_amdgcn_cvt_pk_fp8_f32(f, f, 0, false) & 0xff);
}
// 16B-slot XOR swizzle within a 128B (64-short) row: 2-way banks, no pad.
__device__ __forceinline__ int sw_idx(int row, int kshort) {
  int slot = kshort >> 3;
  return row * 64 + (((slot ^ (row & 7)) << 3) | (kshort & 7));
}

// ---------------------------------------------------------------------------
// 1. Merged launch A: blocks [0,250) bucket edges by dst region;
//    blocks [250,330) byte-packed src histogram.
// ---------------------------------------------------------------------------
__global__ __launch_bounds__(256) void build_a_kernel(
    const int* __restrict__ src, const int* __restrict__ dst,
    const float* __restrict__ ew, int* __restrict__ bcnt,
    uint2* __restrict__ bucket, uint_t* __restrict__ p8src) {
  __shared__ uint_t shm[BSPAN + 2 * NREG];  // bucket: rl+cnt+cur; hist: 6250
  if (blockIdx.x < NB_BUCKET) {
    uint_t* rl = shm;                 // BSPAN
    int* cnt = (int*)(shm + BSPAN);   // NREG
    int* cur = cnt + NREG;            // NREG
    const int e0 = blockIdx.x * BSPAN;

    for (int i = threadIdx.x; i < NREG; i += 256) cnt[i] = 0;
    __syncthreads();

    for (int i = threadIdx.x; i < BSPAN; i += 256) {
      uint_t d = (uint_t)dst[e0 + i];
      uint_t r = d / REG_NODES;
      uint_t loc = d - r * REG_NODES;
      rl[i] = (r << 16) | loc;
      atomicAdd(&cnt[r], 1);
    }
    __syncthreads();

    for (int i = threadIdx.x; i < NREG; i += 256)
      cur[i] = atomicAdd(&bcnt[i], cnt[i]);
    __syncthreads();

    for (int i = threadIdx.x; i < BSPAN; i += 256) {
      uint_t v = rl[i];
      uint_t r = v >> 16, loc = v & 0xffffu;
      int pos = atomicAdd(&cur[r], 1);
      if (pos < BUCKET_CAP)
        bucket[(size_t)r * BUCKET_CAP + pos] = make_uint2(
            (loc << 17) | (uint_t)src[e0 + i], __float_as_uint(ew[e0 + i]));
    }
  } else {
    uint_t* h = shm;
    const int idx = blockIdx.x - NB_BUCKET;
    const int r = idx / HB;
    const int b = idx % HB;
    const uint_t rbase = (uint_t)(r * HNODES);

    for (int i = threadIdx.x; i < HWORDS; i += 256) h[i] = 0u;
    __syncthreads();

    const uint4* k4 = (const uint4*)(src + b * HCHUNK);
    for (int i = threadIdx.x; i < HCHUNK / 4; i += 256) {
      uint4 v = k4[i];
      uint_t t;
      t = v.x - rbase; if (t < (uint_t)HNODES) atomicAdd(&h[t >> 2], 1u << ((t & 3u) * 8u));
      t = v.y - rbase; if (t < (uint_t)HNODES) atomicAdd(&h[t >> 2], 1u << ((t & 3u) * 8u));
      t = v.z - rbase; if (t < (uint_t)HNODES) atomicAdd(&h[t >> 2], 1u << ((t & 3u) * 8u));
      t = v.w - rbase; if (t < (uint_t)HNODES) atomicAdd(&h[t >> 2], 1u << ((t & 3u) * 8u));
    }
    __syncthreads();

    uint_t* outp = p8src + (size_t)b * NWORDS + r * HWORDS;
    for (int i = threadIdx.x; i < HWORDS; i += 256) outp[i] = h[i];
  }
}

// ---------------------------------------------------------------------------
// 2. Merged launch B (1024 threads): blocks [0,160) region place (csr+rc+nd)
//    with 4-aligned per-node slots; blocks [160,185) ns from src histogram.
// ---------------------------------------------------------------------------
__global__ __launch_bounds__(1024) void build_b_kernel(
    const uint2* __restrict__ bucket, const int* __restrict__ bcnt,
    const uint_t* __restrict__ p8src, uint_t* __restrict__ csr,
    int2* __restrict__ rc, float* __restrict__ nd, float* __restrict__ ns) {
  __shared__ uint_t staged[STG_CAP];      // 51.5 KB
  __shared__ int cnt[REG_NODES];
  __shared__ int sc[REG_NODES];
  __shared__ int ts[1024];
  const int tid = threadIdx.x;
  if (blockIdx.x >= NREG) {
    // ns blocks
    int w = (blockIdx.x - NREG) * 1024 + tid;
    if (w >= NWORDS) return;
    int c0 = 0, c1 = 0, c2 = 0, c3 = 0;
    for (int b = 0; b < HB; ++b) {
      uint_t xv = p8src[(size_t)b * NWORDS + w];
      c0 += (int)(xv & 0xffu);
      c1 += (int)((xv >> 8) & 0xffu);
      c2 += (int)((xv >> 16) & 0xffu);
      c3 += (int)((xv >> 24) & 0xffu);
    }
    ((float4*)ns)[w] = make_float4(
        rsqrtf(fmaxf((float)c0, 1.0f)), rsqrtf(fmaxf((float)c1, 1.0f)),
        rsqrtf(fmaxf((float)c2, 1.0f)), rsqrtf(fmaxf((float)c3, 1.0f)));
    return;
  }
  const int r = blockIdx.x;
  const int nE = min(bcnt[r], BUCKET_CAP);
  const int alloc_r = ((nE + 3) & ~3) + RSLACK;

  // csr base = exclusive prefix over region allocs (all multiples of 4)
  ts[tid] = (tid < NREG) ? (((min(bcnt[tid], BUCKET_CAP) + 3) & ~3) + RSLACK) : 0;
  for (int i = tid; i < REG_NODES; i += 1024) cnt[i] = 0;
  __syncthreads();
  for (int off = 1; off < 256; off <<= 1) {
    int t = (tid >= off) ? ts[tid - off] : 0;
    __syncthreads();
    ts[tid] += t;
    __syncthreads();
  }
  const int csr_base = (r == 0) ? 0 : ts[r - 1];
  __syncthreads();

  // pass A: per-node counts
  const uint2* bk = bucket + (size_t)r * BUCKET_CAP;
  for (int i = tid; i < nE; i += 1024) atomicAdd(&cnt[bk[i].x >> 17], 1);
  __syncthreads();

  // exclusive scan over padded (round4) counts (1 node per thread)
  int cv = (tid < REG_NODES) ? cnt[tid] : 0;
  int pv = (cv + 3) & ~3;
  ts[tid] = pv;
  __syncthreads();
  for (int off = 1; off < 1024; off <<= 1) {
    int t = (tid >= off) ? ts[tid - off] : 0;
    __syncthreads();
    ts[tid] += t;
    __syncthreads();
  }
  if (tid < REG_NODES) {
    int run = (tid == 0) ? 0 : ts[tid - 1];
    sc[tid] = run;
    int v = r * REG_NODES + tid;
    rc[v] = make_int2(csr_base + run, cv);
    nd[v] = rsqrtf(fmaxf((float)cv, 1.0f));
  }
  __syncthreads();
  const int ptot = min(ts[1023], STG_CAP);  // padded total (clamp: safety)
  __syncthreads();

  // zero staged (pad entries decode to row 0, w = 0.0 -> exact no-op)
  for (int i = tid; i < ptot; i += 1024) staged[i] = 0u;
  __syncthreads();

  // pass B: place into staged slice
  for (int i = tid; i < nE; i += 1024) {
    uint2 e = bk[i];
    uint_t loc = e.x >> 17;
    int pos = atomicAdd(&sc[loc], 1);
    if (pos < STG_CAP)
      staged[pos] = ((uint_t)(f2bf(__uint_as_float(e.y)) & 0x7fff) << 17) |
                    (e.x & 0x1ffffu);
  }
  __syncthreads();

  // coalesced stream-out
  const int out_len = min(ptot, alloc_r);
  for (int i = tid; i < out_len; i += 1024) csr[csr_base + i] = staged[i];
}

// ---------------------------------------------------------------------------
// 3. MFMA GEMM (layer 1 only): T[i,:] = fp8(ns[i] * (X[i,:] @ W))
// ---------------------------------------------------------------------------
template <int K, bool AFP32>
__global__ __launch_bounds__(256) void gemm_mfma_kernel(
    const void* __restrict__ Xin, const float* __restrict__ W,
    const float* __restrict__ ns, uchar_t* __restrict__ T, int ntiles) {
  constexpr int CH = K / 32;
  constexpr int WROW = K + 8;
  __shared__ __align__(16) ushort_t Wt[64 * WROW];
  const int tid = threadIdx.x;

  for (int i = tid; i < K * 64; i += 256) {
    int k = i >> 6, nn = i & 63;
    Wt[nn * WROW + k] = f2bf(W[i]);
  }
  __syncthreads();

  const int wave = tid >> 6;
  const int lane = tid & 63;
  const int tile = blockIdx.x * 4 + wave;
  if (tile >= ntiles) return;
  const int m = lane & 15;
  const int q = lane >> 4;
  const int node0 = tile * 16;

  short8 afrag[CH];
  if (AFP32) {
    const float* xr = (const float*)Xin + (size_t)(node0 + m) * K + q * 8;
#pragma unroll
    for (int c = 0; c < CH; ++c) {
      float4 xa = *(const float4*)(xr + c * 32);
      float4 xb = *(const float4*)(xr + c * 32 + 4);
      short8 a;
      a[0] = (short)f2bf(xa.x); a[1] = (short)f2bf(xa.y);
      a[2] = (short)f2bf(xa.z); a[3] = (short)f2bf(xa.w);
      a[4] = (short)f2bf(xb.x); a[5] = (short)f2bf(xb.y);
      a[6] = (short)f2bf(xb.z); a[7] = (short)f2bf(xb.w);
      afrag[c] = a;
    }
  } else {
    const ushort_t* xr = (const ushort_t*)Xin + (size_t)(node0 + m) * K + q * 8;
#pragma unroll
    for (int c = 0; c < CH; ++c)
      afrag[c] = *(const short8*)(xr + c * 32);
  }

  floatx4 acc[4];
#pragma unroll
  for (int t = 0; t < 4; ++t) acc[t] = (floatx4){0.f, 0.f, 0.f, 0.f};

#pragma unroll
  for (int t = 0; t < 4; ++t) {
    const ushort_t* wr = &Wt[(t * 16 + m) * WROW + q * 8];
#pragma unroll
    for (int c = 0; c < CH; ++c) {
      short8 bfrag = *(const short8*)(wr + c * 32);
      acc[t] = __builtin_amdgcn_mfma_f32_16x16x32_bf16(afrag[c], bfrag, acc[t], 0, 0, 0);
    }
  }

  float4 nsv = *(const float4*)(ns + node0 + q * 4);
  const float nsa[4] = {nsv.x, nsv.y, nsv.z, nsv.w};
#pragma unroll
  for (int t = 0; t < 4; ++t) {
#pragma unroll
    for (int r = 0; r < 4; ++r) {
      int node = node0 + q * 4 + r;
      T[(size_t)node * 64 + t * 16 + m] = f2fp8(acc[t][r] * nsa[r]);
    }
  }
}

// ---------------------------------------------------------------------------
// 4. Fused gather + next-layer GEMM (or pooling). Single node per thread,
//    uint4 csr loads (4-aligned padded slots), 8-deep T-row batches,
//    compact XOR-swizzled 16KB LDS.
// ---------------------------------------------------------------------------
__device__ __forceinline__ void gacc1(float acc[8], uint_t e, uint2 p) {
  float w = __uint_as_float((e >> 17) << 16);
  floatx2 a;
  a = __builtin_amdgcn_cvt_pk_f32_fp8(p.x, false);
  acc[0] = fmaf(a.x, w, acc[0]); acc[1] = fmaf(a.y, w, acc[1]);
  a = __builtin_amdgcn_cvt_pk_f32_fp8(p.x, true);
  acc[2] = fmaf(a.x, w, acc[2]); acc[3] = fmaf(a.y, w, acc[3]);
  a = __builtin_amdgcn_cvt_pk_f32_fp8(p.y, false);
  acc[4] = fmaf(a.x, w, acc[4]); acc[5] = fmaf(a.y, w, acc[5]);
  a = __builtin_amdgcn_cvt_pk_f32_fp8(p.y, true);
  acc[6] = fmaf(a.x, w, acc[6]); acc[7] = fmaf(a.y, w, acc[7]);
}

template <bool POOL>
__global__ __launch_bounds__(256, 6) void fused_kernel(
    const uint_t* __restrict__ csr, const int2* __restrict__ rc,
    const uchar_t* __restrict__ T, const float* __restrict__ nd,
    const float* __restrict__ bias, const float* __restrict__ ns,
    const float* __restrict__ W, uchar_t* __restrict__ Tout,
    const int* __restrict__ gid, float* __restrict__ pooled) {
  __shared__ __align__(16) ushort_t Hs[POOL ? 8 : 64 * 64];   // 8 KB
  __shared__ __align__(16) ushort_t Wt[POOL ? 8 : 64 * 64];   // 8 KB
  __shared__ float gaccF[POOL ? 4 * 64 : 1];
  __shared__ int g0s;
  const int tid = threadIdx.x;
  const int node_base = blockIdx.x * 64;

  if constexpr (POOL) {
    gaccF[tid] = 0.0f;  // 4*64 == 256
    if (tid == 0) g0s = gid[node_base];
  } else {
    for (int i = tid; i < H_F * 64; i += 256) {
      int k = i >> 6, nn = i & 63;
      Wt[sw_idx(nn, k)] = f2bf(W[i]);
    }
  }
  __syncthreads();

  const int lane = tid & 63;
  const int wv = tid >> 6;
  const int o = lane >> 3, l = lane & 7;
  const uint2* Tp = (const uint2*)T;

  const float4 b0 = *(const float4*)&bias[l * 8];
  const float4 b1v = *(const float4*)&bias[l * 8 + 4];

#pragma unroll 1
  for (int pass = 0; pass < 2; ++pass) {
    const int ln = pass * 32 + wv * 8 + o;
    const int v = node_base + ln;
    if (v < N_NODES) {
      int2 rcv = rc[v];
      const uint4* c4 = (const uint4*)(csr + rcv.x);
      const int nb4 = (rcv.y + 3) >> 2;

      float acc[8] = {0, 0, 0, 0, 0, 0, 0, 0};
      int kq = 0;
      for (; kq + 2 <= nb4; kq += 2) {
        uint4 ea = c4[kq];
        uint4 eb = c4[kq + 1];
        uint2 p0 = Tp[(size_t)(ea.x & 0x1ffffu) * 8 + l];
        uint2 p1 = Tp[(size_t)(ea.y & 0x1ffffu) * 8 + l];
        uint2 p2 = Tp[(size_t)(ea.z & 0x1ffffu) * 8 + l];
        uint2 p3 = Tp[(size_t)(ea.w & 0x1ffffu) * 8 + l];
        uint2 p4 = Tp[(size_t)(eb.x & 0x1ffffu) * 8 + l];
        uint2 p5 = Tp[(size_t)(eb.y & 0x1ffffu) * 8 + l];
        uint2 p6 = Tp[(size_t)(eb.z & 0x1ffffu) * 8 + l];
        uint2 p7 = Tp[(size_t)(eb.w & 0x1ffffu) * 8 + l];
        gacc1(acc, ea.x, p0); gacc1(acc, ea.y, p1);
        gacc1(acc, ea.z, p2); gacc1(acc, ea.w, p3);
        gacc1(acc, eb.x, p4); gacc1(acc, eb.y, p5);
        gacc1(acc, eb.z, p6); gacc1(acc, eb.w, p7);
      }
      if (kq < nb4) {
        uint4 ea = c4[kq];
        uint2 p0 = Tp[(size_t)(ea.x & 0x1ffffu) * 8 + l];
        uint2 p1 = Tp[(size_t)(ea.y & 0x1ffffu) * 8 + l];
        uint2 p2 = Tp[(size_t)(ea.z & 0x1ffffu) * 8 + l];
        uint2 p3 = Tp[(size_t)(ea.w & 0x1ffffu) * 8 + l];
        gacc1(acc, ea.x, p0); gacc1(acc, ea.y, p1);
        gacc1(acc, ea.z, p2); gacc1(acc, ea.w, p3);
      }

      const float ndv = nd[v];
      if constexpr (!POOL) {
        uint4 ov;
        ov.x = (uint_t)f2bf(fmaxf(fmaf(acc[0], ndv, b0.x), 0.f)) |
               ((uint_t)f2bf(fmaxf(fmaf(acc[1], ndv, b0.y), 0.f)) << 16);
        ov.y = (uint_t)f2bf(fmaxf(fmaf(acc[2], ndv, b0.z), 0.f)) |
               ((uint_t)f2bf(fmaxf(fmaf(acc[3], ndv, b0.w), 0.f)) << 16);
        ov.z = (uint_t)f2bf(fmaxf(fmaf(acc[4], ndv, b1v.x), 0.f)) |
               ((uint_t)f2bf(fmaxf(fmaf(acc[5], ndv, b1v.y), 0.f)) << 16);
        ov.w = (uint_t)f2bf(fmaxf(fmaf(acc[6], ndv, b1v.z), 0.f)) |
               ((uint_t)f2bf(fmaxf(fmaf(acc[7], ndv, b1v.w), 0.f)) << 16);
        *((uint4*)&Hs[sw_idx(ln, l * 8)]) = ov;
      } else {
        const float bb[8] = {b0.x, b0.y, b0.z, b0.w, b1v.x, b1v.y, b1v.z, b1v.w};
        float vals[8];
#pragma unroll
        for (int f = 0; f < 8; ++f)
          vals[f] = bflo((uint_t)f2bf(fmaxf(fmaf(acc[f], ndv, bb[f]), 0.f)));
        int g = gid[v];
        int gl = g - g0s;
        if (gl >= 0 && gl < 4) {
#pragma unroll
          for (int f = 0; f < 8; ++f)
            atomicAdd(&gaccF[gl * 64 + l * 8 + f], vals[f]);
        } else {
#pragma unroll
          for (int f = 0; f < 8; ++f)
            atomicAdd(&pooled[(size_t)g * 64 + l * 8 + f], vals[f]);
        }
      }
    }
  }
  __syncthreads();

  if constexpr (!POOL) {
    const int m = lane & 15, q = lane >> 4;
    const int node0 = node_base + wv * 16;
    if (node0 < N_NODES) {  // N % 16 == 0, so node0 < N implies a full tile
      short8 afrag[2];
      afrag[0] = *(const short8*)&Hs[sw_idx(wv * 16 + m, q * 8)];
      afrag[1] = *(const short8*)&Hs[sw_idx(wv * 16 + m, q * 8 + 32)];

      floatx4 acc4v[4];
#pragma unroll
      for (int t = 0; t < 4; ++t) acc4v[t] = (floatx4){0.f, 0.f, 0.f, 0.f};
#pragma unroll
      for (int t = 0; t < 4; ++t) {
#pragma unroll
        for (int c = 0; c < 2; ++c) {
          short8 bfrag = *(const short8*)&Wt[sw_idx(t * 16 + m, q * 8 + c * 32)];
          acc4v[t] = __builtin_amdgcn_mfma_f32_16x16x32_bf16(afrag[c], bfrag,
                                                            acc4v[t], 0, 0, 0);
        }
      }
      float4 nsv = *(const float4*)(ns + node0 + q * 4);
      const float nsa[4] = {nsv.x, nsv.y, nsv.z, nsv.w};
#pragma unroll
      for (int t = 0; t < 4; ++t) {
#pragma unroll
        for (int r2 = 0; r2 < 4; ++r2) {
          int node = node0 + q * 4 + r2;
          Tout[(size_t)node * 64 + t * 16 + m] = f2fp8(acc4v[t][r2] * nsa[r2]);
        }
      }
    }
  } else {
    int vlast = node_base + 63;
    if (vlast >= N_NODES) vlast = N_NODES - 1;
    int span = gid[vlast] - g0s + 1;
    if (span > 4) span = 4;
    if (tid < span * 64) {
      int gl = tid >> 6, j = tid & 63;
      int g = g0s + gl;
      if (g < G_GRAPHS) {
        float vsum = gaccF[gl * 64 + j];
        if (vsum != 0.0f) atomicAdd(&pooled[(size_t)g * 64 + j], vsum);
      }
    }
  }
}

// ---------------------------------------------------------------------------
// 5. Tiny pool finalize + MLP: reads pooled[G][64] (64 KB) instead of H.
// ---------------------------------------------------------------------------
__global__ __launch_bounds__(256) void pool_mlp_kernel(
    const float* __restrict__ pooled, const int* __restrict__ gid,
    const float* __restrict__ Dw1, const float* __restrict__ Db1,
    const float* __restrict__ Dw2, const float* __restrict__ Db2,
    const float* __restrict__ Dw3, const float* __restrict__ Db3,
    float* __restrict__ out) {
  __shared__ float mean[64];
  __shared__ float h1s[16], h2s[8];
  const int g = blockIdx.x;
  int l = 0, r = N_NODES;
  while (l < r) { int m = (l + r) >> 1; if (gid[m] < g) l = m + 1; else r = m; }
  const int lo = l;
  r = N_NODES;
  while (l < r) { int m = (l + r) >> 1; if (gid[m] < g + 1) l = m + 1; else r = m; }
  const int hi = l;

  if (threadIdx.x < 64) {
    float inv = 1.0f / fmaxf((float)(hi - lo), 1.0f);
    mean[threadIdx.x] = pooled[(size_t)g * 64 + threadIdx.x] * inv;
  }
  __syncthreads();
  if (threadIdx.x < 16) {
    int o = threadIdx.x;
    float a = Db1[o];
#pragma unroll
    for (int k = 0; k < 64; ++k) a = fmaf(mean[k], Dw1[k * 16 + o], a);
    h1s[o] = fmaxf(a, 0.0f);
  }
  __syncthreads();
  if (threadIdx.x < 8) {
    int o = threadIdx.x;
    float a = Db2[o];
#pragma unroll
    for (int k = 0; k < 16; ++k) a = fmaf(h1s[k], Dw2[k * 8 + o], a);
    h2s[o] = fmaxf(a, 0.0f);
  }
  __syncthreads();
  if (threadIdx.x == 0) {
    float a = Db3[0];
#pragma unroll
    for (int k = 0; k < 8; ++k) a = fmaf(h2s[k], Dw3[k], a);
    out[g] = 1.0f / (1.0f + expf(-a));
  }
}

// ---------------------------------------------------------------------------
extern "C" void kernel_launch(void* const* d_in, const int* in_sizes, int n_in,
                              void* d_out, int out_size, void* d_ws, size_t ws_size,
                              hipStream_t stream) {
  const float* x   = (const float*)d_in[0];
  const int*   src = (const int*)  d_in[1];
  const int*   dst = (const int*)  d_in[2];
  const float* ew  = (const float*)d_in[3];
  const int*   gid = (const int*)  d_in[4];
  const float* W1  = (const float*)d_in[5];
  const float* b1  = (const float*)d_in[6];
  const float* W2  = (const float*)d_in[7];
  const float* b2  = (const float*)d_in[8];
  const float* W3  = (const float*)d_in[9];
  const float* b3  = (const float*)d_in[10];
  const float* Dw1 = (const float*)d_in[11];
  const float* Db1 = (const float*)d_in[12];
  const float* Dw2 = (const float*)d_in[13];
  const float* Db2 = (const float*)d_in[14];
  const float* Dw3 = (const float*)d_in[15];
  const float* Db3 = (const float*)d_in[16];
  float* out = (float*)d_out;

  // workspace layout
  char* ws = (char*)d_ws;
  const size_t TSZ = (size_t)N_NODES * 64;                   // 6.4 MB
  const size_t BUCKET_BYTES = (size_t)NREG * BUCKET_CAP * 8; // 14.08 MB
  uchar_t*  T_a   = (uchar_t*)ws;                            // 6.4 MB
  uchar_t*  T_b   = (uchar_t*)(ws + TSZ);                    // 6.4 MB
  uint2*    bucket = (uint2*)ws;         // aliases T_a/T_b (dead after build_b)
  char* p = ws + BUCKET_BYTES;
  uint_t*   csr   = (uint_t*)p;          p += (size_t)CSR_ALLOC * 4;    // 7.2 MB
  uint_t*   p8src = (uint_t*)p;          p += (size_t)HB * NWORDS * 4;  // 2 MB
  float*    ns    = (float*)p;           p += (size_t)N_NODES * 4;
  float*    nd    = (float*)p;           p += (size_t)N_NODES * 4;
  int2*     rc    = (int2*)p;            p += (size_t)N_NODES * 8;
  int*      bcnt  = (int*)p;             p += (size_t)NREG * 4;
  float*    pooled = (float*)p;          // 64 KB, contiguous after bcnt

  const int NTILES  = N_NODES / 16;                          // 6250
  const int NB_A    = NB_BUCKET + HR * HB;                   // 250+80 = 330
  const int NB_B    = NREG + (NWORDS + 1023) / 1024;         // 160+25 = 185
  const int NB_GEMM = (NTILES + 3) / 4;
  const int NB_F    = (N_NODES + 63) / 64;                   // 1563

  // ---- CSR build (2 merged launches + zero bcnt AND pooled in one memset)
  hipMemsetAsync(bcnt, 0,
                 NREG * sizeof(int) + G_GRAPHS * H_F * sizeof(float), stream);
  build_a_kernel<<<NB_A, 256, 0, stream>>>(src, dst, ew, bcnt, bucket, p8src);
  build_b_kernel<<<NB_B, 1024, 0, stream>>>(bucket, bcnt, p8src, csr, rc, nd, ns);

  // ---- layer 1: x(fp32,128) -> T_a   (overwrites bucket alias, post build_b)
  gemm_mfma_kernel<IN_F, true><<<NB_GEMM, 256, 0, stream>>>(x, W1, ns, T_a, NTILES);
  // ---- fused gather(L1)+gemm(L2): T_a -> T_b
  fused_kernel<false><<<NB_F, 256, 0, stream>>>(csr, rc, T_a, nd, b1, ns, W2,
                                                T_b, nullptr, nullptr);
  // ---- fused gather(L2)+gemm(L3): T_b -> T_a
  fused_kernel<false><<<NB_F, 256, 0, stream>>>(csr, rc, T_b, nd, b2, ns, W3,
                                                T_a, nullptr, nullptr);
  // ---- fused gather(L3)+pool: T_a -> pooled
  fused_kernel<true><<<NB_F, 256, 0, stream>>>(csr, rc, T_a, nd, b3, nullptr,
                                               nullptr, nullptr, gid, pooled);

  // ---- finalize pool + MLP
  pool_mlp_kernel<<<G_GRAPHS, 256, 0, stream>>>(pooled, gid, Dw1, Db1, Dw2, Db2,
                                                Dw3, Db3, out);
}